// Round 2
// baseline (15028.819 us; speedup 1.0000x reference)
//
#include <hip/hip_runtime.h>
#include <hip/hip_bf16.h>
#include <math.h>

#define NN 3
#define BB 4
#define CC 256
#define C2 512
#define HH 40
#define WW 40
#define PP 1600
#define NBB 12                  // NN*BB
#define NODESZ (NBB*CC*PP)      // 4,915,200 floats
#define TP 8                    // attention: pixels per block
#define TO 16                   // theta: output channels per block
#define TCO 8                   // conv: output channels per block

__global__ void k_copy(const float* __restrict__ in, float* __restrict__ out) {
  int i = blockIdx.x * 256 + threadIdx.x;
  out[i] = in[i];
}

// th[nb,o,p] = tb[o] + sum_c tw[o,c] * nodes[nb,c,p]
__global__ void k_theta(const float* __restrict__ nodes, const float* __restrict__ tw,
                        const float* __restrict__ tb, float* __restrict__ th) {
  __shared__ float w[TO * CC];
  int t = threadIdx.x;
  int nb = blockIdx.y / (CC / TO);
  int o0 = (blockIdx.y % (CC / TO)) * TO;
  for (int i = t; i < TO * CC; i += 320) w[i] = tw[(o0 + (i >> 8)) * CC + (i & 255)];
  __syncthreads();
  int p = blockIdx.x * 320 + t;
  const float* src = nodes + nb * CC * PP + p;
  float acc[TO];
#pragma unroll
  for (int o = 0; o < TO; ++o) acc[o] = tb[o0 + o];
  for (int c = 0; c < CC; c += 4) {
    float v0 = src[c * PP], v1 = src[(c + 1) * PP], v2 = src[(c + 2) * PP], v3 = src[(c + 3) * PP];
#pragma unroll
    for (int o = 0; o < TO; ++o) {
      const float4 ww = *(const float4*)(w + o * CC + c);
      acc[o] += ww.x * v0 + ww.y * v1 + ww.z * v2 + ww.w * v3;
    }
  }
#pragma unroll
  for (int o = 0; o < TO; ++o) th[nb * CC * PP + (o0 + o) * PP + p] = acc[o];
}

// For receiver n, block of TP pixels p0..p0+7:
//  per sender j!=n: sc[k][q] = sum_c th[n,c,p0+k]*nodes[j,c,q]; softmax over q;
//  acc[k][c] += sum_q atn*(nodes[j,c,q]+nodes[n,c,q])
__global__ void k_attn(const float* __restrict__ nodes, const float* __restrict__ th,
                       float* __restrict__ agg) {
  __shared__ __align__(16) float thi[TP * CC];   // 8 KB
  __shared__ __align__(16) float sc[TP * PP];    // 51.2 KB
  __shared__ float inv_s[TP];
  int t = threadIdx.x;
  int nb = blockIdx.y;
  int n = nb / BB;
  int b = nb - n * BB;
  int p0 = blockIdx.x * TP;
  for (int i = t; i < TP * CC; i += 256) {
    int k = i >> 8, c = i & 255;
    thi[i] = th[nb * CC * PP + c * PP + p0 + k];
  }
  const float* ei = nodes + nb * CC * PP;
  float acc[TP];
#pragma unroll
  for (int k = 0; k < TP; ++k) acc[k] = 0.f;

  for (int j = 0; j < NN; ++j) {
    if (j == n) continue;
    const float* ej = nodes + (j * BB + b) * CC * PP;
    __syncthreads();                       // thi visible / sc free for overwrite
    // ---- scores ----
    for (int q = t; q < PP; q += 256) {
      float s[TP];
#pragma unroll
      for (int k = 0; k < TP; ++k) s[k] = 0.f;
      const float* ejq = ej + q;
      for (int c = 0; c < CC; c += 4) {
        float e0 = ejq[c * PP], e1 = ejq[(c + 1) * PP], e2 = ejq[(c + 2) * PP], e3 = ejq[(c + 3) * PP];
#pragma unroll
        for (int k = 0; k < TP; ++k) {
          const float4 tw4 = *(const float4*)(thi + k * CC + c);
          s[k] += tw4.x * e0 + tw4.y * e1 + tw4.z * e2 + tw4.w * e3;
        }
      }
#pragma unroll
      for (int k = 0; k < TP; ++k) sc[k * PP + q] = s[k];
    }
    __syncthreads();
    // ---- softmax: 32-lane group per row ----
    {
      int r = t >> 5, lq = t & 31;
      float m = -3.0e38f;
      for (int q = lq; q < PP; q += 32) m = fmaxf(m, sc[r * PP + q]);
#pragma unroll
      for (int o = 16; o > 0; o >>= 1) m = fmaxf(m, __shfl_down(m, o, 32));
      m = __shfl(m, 0, 32);
      float ls = 0.f;
      for (int q = lq; q < PP; q += 32) {
        float e = __expf(sc[r * PP + q] - m);
        sc[r * PP + q] = e;
        ls += e;
      }
#pragma unroll
      for (int o = 16; o > 0; o >>= 1) ls += __shfl_down(ls, o, 32);
      if (lq == 0) inv_s[r] = 1.f / ls;
    }
    __syncthreads();
    // ---- weighted accumulate: thread t = channel t ----
    const float4* ej4 = (const float4*)(ej + t * PP);
    const float4* ei4 = (const float4*)(ei + t * PP);
    float part[TP];
#pragma unroll
    for (int k = 0; k < TP; ++k) part[k] = 0.f;
    for (int q4 = 0; q4 < PP / 4; ++q4) {
      float4 a = ej4[q4], c4 = ei4[q4];
      float v0 = a.x + c4.x, v1 = a.y + c4.y, v2 = a.z + c4.z, v3 = a.w + c4.w;
#pragma unroll
      for (int k = 0; k < TP; ++k) {
        const float4 s4 = *((const float4*)(sc + k * PP) + q4);
        part[k] += s4.x * v0 + s4.y * v1 + s4.z * v2 + s4.w * v3;
      }
    }
#pragma unroll
    for (int k = 0; k < TP; ++k) acc[k] += part[k] * inv_s[k];
  }
#pragma unroll
  for (int k = 0; k < TP; ++k) agg[nb * CC * PP + t * PP + p0 + k] = acc[k];
}

// conv3x3 over concat([xin(256ch), hin(256ch)]) -> CO_TOTAL channels, ACT 0=sigmoid 1=tanh
template <int CO_TOTAL, int ACT>
__global__ void k_conv(const float* __restrict__ xin, const float* __restrict__ hin,
                       int h_stride, const float* __restrict__ w,
                       const float* __restrict__ b, float* __restrict__ out) {
  __shared__ float win[10 * 42];
  int t = threadIdx.x;
  int nb = blockIdx.y / (CO_TOTAL / TCO);
  int co0 = (blockIdx.y % (CO_TOTAL / TCO)) * TCO;
  int y0 = blockIdx.x * 8;
  int ly = t / 40, lx = t - ly * 40;
  float acc[TCO];
#pragma unroll
  for (int i = 0; i < TCO; ++i) acc[i] = b[co0 + i];
  const float* xb = xin + nb * CC * PP;
  const float* hb = hin + (size_t)nb * h_stride;
  for (int ci = 0; ci < C2; ++ci) {
    const float* plane = (ci < CC) ? (xb + ci * PP) : (hb + (ci - CC) * PP);
    __syncthreads();
    for (int i = t; i < 420; i += 320) {
      int wy = i / 42, wx = i - wy * 42;
      int yy = y0 - 1 + wy, xx = wx - 1;
      float v = 0.f;
      if ((unsigned)yy < (unsigned)HH && (unsigned)xx < (unsigned)WW) v = plane[yy * WW + xx];
      win[i] = v;
    }
    __syncthreads();
    const float* wrow = w + ((size_t)co0 * C2 + ci) * 9;
#pragma unroll
    for (int co = 0; co < TCO; ++co) {
      const float* wc = wrow + (size_t)co * C2 * 9;
#pragma unroll
      for (int ky = 0; ky < 3; ++ky)
#pragma unroll
        for (int kx = 0; kx < 3; ++kx)
          acc[co] += wc[ky * 3 + kx] * win[(ly + ky) * 42 + (lx + kx)];
    }
  }
  int p = (y0 + ly) * WW + lx;
#pragma unroll
  for (int co = 0; co < TCO; ++co) {
    float v = acc[co];
    v = ACT ? tanhf(v) : 1.f / (1.f + __expf(-v));
    out[(size_t)nb * CO_TOTAL * PP + (co0 + co) * PP + p] = v;
  }
}

// overwrite r-slot (channels 0..255 of gates) with r*h
__global__ void k_rh(float* __restrict__ gates, const float* __restrict__ nodes) {
  int i = blockIdx.x * 256 + threadIdx.x;   // over NODESZ
  int nb = i / (CC * PP);
  int rem = i - nb * (CC * PP);
  int ga = nb * C2 * PP + rem;
  gates[ga] = gates[ga] * nodes[i];
}

// h_new = (1-z)*h + z*cand
__global__ void k_update(const float* __restrict__ gates, const float* __restrict__ cand,
                         float* __restrict__ nodes) {
  int i = blockIdx.x * 256 + threadIdx.x;   // NODESZ
  int nb = i / (CC * PP);
  int rem = i - nb * (CC * PP);
  float z = gates[nb * C2 * PP + CC * PP + rem];
  float h = nodes[i];
  nodes[i] = (1.f - z) * h + z * cand[i];
}

extern "C" void kernel_launch(void* const* d_in, const int* in_sizes, int n_in,
                              void* d_out, int out_size, void* d_ws, size_t ws_size,
                              hipStream_t stream) {
  const float* nodes_in = (const float*)d_in[0];
  const float* tw = (const float*)d_in[1];
  const float* tb = (const float*)d_in[2];
  const float* gw = (const float*)d_in[3];
  const float* gb = (const float*)d_in[4];
  const float* cw = (const float*)d_in[5];
  const float* cb = (const float*)d_in[6];

  float* nodes = (float*)d_out;             // state lives in d_out (NODESZ fp32)
  float* th    = (float*)d_ws;              // 19.66 MB (reused as cand)
  float* agg   = th + NODESZ;               // 19.66 MB
  float* gates = agg + NODESZ;              // 39.32 MB
  // ws use: 78.6 MB

  k_copy<<<NODESZ / 256, 256, 0, stream>>>(nodes_in, nodes);
  for (int pass = 0; pass < 2; ++pass) {
    k_theta<<<dim3(5, NBB * (CC / TO)), 320, 0, stream>>>(nodes, tw, tb, th);
    k_attn<<<dim3(PP / TP, NBB), 256, 0, stream>>>(nodes, th, agg);
    k_conv<C2, 0><<<dim3(5, NBB * (C2 / TCO)), 320, 0, stream>>>(agg, nodes, CC * PP, gw, gb, gates);
    k_rh<<<NODESZ / 256, 256, 0, stream>>>(gates, nodes);
    k_conv<CC, 1><<<dim3(5, NBB * (CC / TCO)), 320, 0, stream>>>(agg, gates, C2 * PP, cw, cb, th);
    k_update<<<NODESZ / 256, 256, 0, stream>>>(gates, th, nodes);
  }
}

// Round 3
// 9615.504 us; speedup vs baseline: 1.5630x; 1.5630x over previous
//
#include <hip/hip_runtime.h>
#include <hip/hip_bf16.h>
#include <math.h>

#define NN 3
#define BB 4
#define CC 256
#define C2 512
#define HH 40
#define WW 40
#define PP 1600
#define NBB 12                  // NN*BB
#define NODESZ (NBB*CC*PP)      // 4,915,200
#define TO 16                   // theta: output channels per block
#define TCO 8                   // conv: output channels per block

typedef short short8 __attribute__((ext_vector_type(8)));
typedef float f32x4 __attribute__((ext_vector_type(4)));
typedef unsigned short ushort_t;
typedef unsigned int uint_t;

__device__ __forceinline__ ushort_t f2bf(float x) {
  union { float f; uint_t u; } v; v.f = x;
  uint_t r = v.u + 0x7fff + ((v.u >> 16) & 1);
  return (ushort_t)(r >> 16);
}

__global__ void k_copy(const float* __restrict__ in, float* __restrict__ out) {
  int i = blockIdx.x * 256 + threadIdx.x;
  out[i] = in[i];
}

// th_t[nb][p][c] (bf16) = tb[o] + sum_c tw[o,c] * nodes[nb,c,p]
__global__ void k_theta(const float* __restrict__ nodes, const float* __restrict__ tw,
                        const float* __restrict__ tb, ushort_t* __restrict__ th_t) {
  __shared__ float w[TO * CC];
  int t = threadIdx.x;
  int nb = blockIdx.y / (CC / TO);
  int o0 = (blockIdx.y % (CC / TO)) * TO;
  for (int i = t; i < TO * CC; i += 320) w[i] = tw[(o0 + (i >> 8)) * CC + (i & 255)];
  __syncthreads();
  int p = blockIdx.x * 320 + t;
  const float* src = nodes + nb * CC * PP + p;
  float acc[TO];
#pragma unroll
  for (int o = 0; o < TO; ++o) acc[o] = tb[o0 + o];
  for (int c = 0; c < CC; c += 4) {
    float v0 = src[c * PP], v1 = src[(c + 1) * PP], v2 = src[(c + 2) * PP], v3 = src[(c + 3) * PP];
#pragma unroll
    for (int o = 0; o < TO; ++o) {
      const float4 ww = *(const float4*)(w + o * CC + c);
      acc[o] += ww.x * v0 + ww.y * v1 + ww.z * v2 + ww.w * v3;
    }
  }
  size_t base = ((size_t)nb * PP + p) * CC + o0;
#pragma unroll
  for (int o = 0; o < TO; o += 2) {
    uint_t lo = f2bf(acc[o]), hi = f2bf(acc[o + 1]);
    *(uint_t*)&th_t[base + o] = lo | (hi << 16);
  }
}

// nodes [12][256][1600] fp32 -> nodes_bf_t [12][1600][256] bf16 (transpose)
__global__ void k_to_bf_t(const float* __restrict__ src, ushort_t* __restrict__ dst) {
  __shared__ float tile[32][33];
  int nb = blockIdx.z;
  int c0 = blockIdx.y * 32;
  int pp0 = blockIdx.x * 32;
  int tx = threadIdx.x & 31, ty = threadIdx.x >> 5;
#pragma unroll
  for (int i = 0; i < 4; ++i)
    tile[ty + 8 * i][tx] = src[((size_t)nb * CC + c0 + ty + 8 * i) * PP + pp0 + tx];
  __syncthreads();
#pragma unroll
  for (int i = 0; i < 4; ++i)
    dst[((size_t)nb * PP + pp0 + ty + 8 * i) * CC + c0 + tx] = f2bf(tile[tx][ty + 8 * i]);
}

// v_all[e][b][c][p] (bf16) = nodes[recv(e),b,c,p] + nodes[send(e),b,c,p]
__global__ void k_prep_v(const float* __restrict__ nodes, ushort_t* __restrict__ v_all) {
  int i = blockIdx.x * 256 + threadIdx.x;   // 6*4*256*1600
  int eb = i / (CC * PP);
  int rem = i - eb * (CC * PP);
  int e = eb >> 2, b = eb & 3;
  int n = e >> 1, jidx = e & 1;
  int js = jidx + (jidx >= n ? 1 : 0);
  float v = nodes[((size_t)(n * BB + b)) * CC * PP + rem] +
            nodes[((size_t)(js * BB + b)) * CC * PP + rem];
  v_all[i] = f2bf(v);
}

// Fused flash attention: S = th.ej^T (per q-tile), online softmax, O += P.V
// Block: (p-tile 64, nb, jidx). Output: agg_t[jidx][nb][p][c] fp32 (plain stores).
__global__ __launch_bounds__(256, 2) void k_attn_mfma(
    const ushort_t* __restrict__ nodes_bf_t,  // [12][1600][256]
    const ushort_t* __restrict__ th_t,        // [12][1600][256]
    const ushort_t* __restrict__ v_all,       // [6][4][256][1600]
    float* __restrict__ agg_t)                // [2][12][1600][256]
{
  __shared__ float Sf[64 * 36];
  __shared__ ushort_t Sp[64 * 40];
  __shared__ float Mst[64], Lst[64], Al[64];

  const int t = threadIdx.x;
  const int w = t >> 6;
  const int l = t & 63;
  const int quad = l >> 4;
  const int l16 = l & 15;
  const int p0 = blockIdx.x * 64;
  const int nb = blockIdx.y;
  const int jidx = blockIdx.z;
  const int n = nb >> 2, b = nb & 3;
  const int e = n * 2 + jidx;
  const int js = jidx + (jidx >= n ? 1 : 0);

  const ushort_t* thp = th_t + ((size_t)nb * PP + p0) * CC;
  const ushort_t* ejq = nodes_bf_t + ((size_t)(js * BB + b) * PP) * CC;  // [q][c]
  const ushort_t* vp  = v_all + ((size_t)(e * BB + b) * CC) * PP;        // [c][q]

  if (t < 64) { Mst[t] = -3.0e38f; Lst[t] = 0.f; }

  // resident A-frags of th: m = 16*w + l16 (16 rows per wave), k = c
  short8 Ath[8];
  {
    const ushort_t* arow = thp + (size_t)(16 * w + l16) * CC + quad * 8;
#pragma unroll
    for (int ks = 0; ks < 8; ++ks) Ath[ks] = *(const short8*)(arow + ks * 32);
  }
  __syncthreads();   // Mst/Lst init visible

  f32x4 O[4][4];
#pragma unroll
  for (int mt = 0; mt < 4; ++mt)
#pragma unroll
    for (int nt = 0; nt < 4; ++nt)
#pragma unroll
      for (int r = 0; r < 4; ++r) O[mt][nt][r] = 0.f;

  for (int q0 = 0; q0 < PP; q0 += 32) {
    // ---- S-GEMM: wave w computes rows [16w,16w+16) x 32 q-cols ----
    f32x4 S0, S1;
#pragma unroll
    for (int r = 0; r < 4; ++r) { S0[r] = 0.f; S1[r] = 0.f; }
    const ushort_t* brow = ejq + (size_t)(q0 + l16) * CC + quad * 8;
#pragma unroll
    for (int ks = 0; ks < 8; ++ks) {
      short8 B0 = *(const short8*)(brow + ks * 32);
      short8 B1 = *(const short8*)(brow + 16 * CC + ks * 32);
      S0 = __builtin_amdgcn_mfma_f32_16x16x32_bf16(Ath[ks], B0, S0, 0, 0, 0);
      S1 = __builtin_amdgcn_mfma_f32_16x16x32_bf16(Ath[ks], B1, S1, 0, 0, 0);
    }
    {
      int srow = 16 * w + quad * 4;
#pragma unroll
      for (int r = 0; r < 4; ++r) {
        Sf[(srow + r) * 36 + l16] = S0[r];
        Sf[(srow + r) * 36 + 16 + l16] = S1[r];
      }
    }
    __syncthreads();
    // ---- online softmax: 4 threads per row, 8 cols each ----
    {
      int r = t >> 2, g = (t & 3) * 8;
      float* row = Sf + r * 36 + g;
      float m = row[0];
#pragma unroll
      for (int k = 1; k < 8; ++k) m = fmaxf(m, row[k]);
      m = fmaxf(m, __shfl_xor(m, 1));
      m = fmaxf(m, __shfl_xor(m, 2));
      float Mo = Mst[r];
      float Mn = fmaxf(Mo, m);
      float alpha = __expf(Mo - Mn);
      float s = 0.f;
      ushort_t* sp = Sp + r * 40 + g;
#pragma unroll
      for (int k = 0; k < 8; ++k) {
        float ev = __expf(row[k] - Mn);
        s += ev;
        sp[k] = f2bf(ev);
      }
      s += __shfl_xor(s, 1);
      s += __shfl_xor(s, 2);
      if ((t & 3) == 0) { Lst[r] = Lst[r] * alpha + s; Mst[r] = Mn; Al[r] = alpha; }
    }
    __syncthreads();
    // ---- rescale O, then PV mfma ----
#pragma unroll
    for (int mt = 0; mt < 4; ++mt) {
#pragma unroll
      for (int r = 0; r < 4; ++r) {
        float a = Al[16 * mt + quad * 4 + r];
#pragma unroll
        for (int nt = 0; nt < 4; ++nt) O[mt][nt][r] *= a;
      }
    }
    short8 Ap[4], Bv[4];
#pragma unroll
    for (int mt = 0; mt < 4; ++mt)
      Ap[mt] = *(const short8*)(Sp + (16 * mt + l16) * 40 + quad * 8);
    {
      const ushort_t* vrow = vp + (size_t)(64 * w + l16) * PP + q0 + quad * 8;
#pragma unroll
      for (int nt = 0; nt < 4; ++nt)
        Bv[nt] = *(const short8*)(vrow + (size_t)(16 * nt) * PP);
    }
#pragma unroll
    for (int mt = 0; mt < 4; ++mt)
#pragma unroll
      for (int nt = 0; nt < 4; ++nt)
        O[mt][nt] = __builtin_amdgcn_mfma_f32_16x16x32_bf16(Ap[mt], Bv[nt], O[mt][nt], 0, 0, 0);
    __syncthreads();   // Sf/Sp/Al reuse next iteration
  }
  // ---- epilogue: normalize by 1/L, plain store to agg_t[jidx] ----
  float* ao = agg_t + (((size_t)jidx * NBB + nb) * PP + p0) * CC;
#pragma unroll
  for (int mt = 0; mt < 4; ++mt) {
#pragma unroll
    for (int r = 0; r < 4; ++r) {
      int m = 16 * mt + quad * 4 + r;
      float inv = 1.f / Lst[m];
      float* dst = ao + (size_t)m * CC + 64 * w + l16;
#pragma unroll
      for (int nt = 0; nt < 4; ++nt) dst[16 * nt] = O[mt][nt][r] * inv;
    }
  }
}

// agg[nb][c][p] = agg_t[0][nb][p][c] + agg_t[1][nb][p][c]   (transpose + sum)
__global__ void k_aggsum_t(const float* __restrict__ agg_t, float* __restrict__ agg) {
  __shared__ float tile[32][33];
  int nb = blockIdx.z;
  int pp0 = blockIdx.y * 32;
  int c0 = blockIdx.x * 32;
  int tx = threadIdx.x & 31, ty = threadIdx.x >> 5;
  const float* a0 = agg_t + ((size_t)nb * PP) * CC;
  const float* a1 = agg_t + ((size_t)(NBB + nb) * PP) * CC;
#pragma unroll
  for (int i = 0; i < 4; ++i) {
    size_t idx = (size_t)(pp0 + ty + 8 * i) * CC + c0 + tx;
    tile[ty + 8 * i][tx] = a0[idx] + a1[idx];
  }
  __syncthreads();
#pragma unroll
  for (int i = 0; i < 4; ++i)
    agg[((size_t)nb * CC + c0 + ty + 8 * i) * PP + pp0 + tx] = tile[tx][ty + 8 * i];
}

// conv3x3 over concat([xin(256ch), hin(256ch)]) -> CO_TOTAL channels, ACT 0=sigmoid 1=tanh
template <int CO_TOTAL, int ACT>
__global__ void k_conv(const float* __restrict__ xin, const float* __restrict__ hin,
                       int h_stride, const float* __restrict__ w,
                       const float* __restrict__ b, float* __restrict__ out) {
  __shared__ float win[10 * 42];
  int t = threadIdx.x;
  int nb = blockIdx.y / (CO_TOTAL / TCO);
  int co0 = (blockIdx.y % (CO_TOTAL / TCO)) * TCO;
  int y0 = blockIdx.x * 8;
  int ly = t / 40, lx = t - ly * 40;
  float acc[TCO];
#pragma unroll
  for (int i = 0; i < TCO; ++i) acc[i] = b[co0 + i];
  const float* xb = xin + nb * CC * PP;
  const float* hb = hin + (size_t)nb * h_stride;
  for (int ci = 0; ci < C2; ++ci) {
    const float* plane = (ci < CC) ? (xb + ci * PP) : (hb + (ci - CC) * PP);
    __syncthreads();
    for (int i = t; i < 420; i += 320) {
      int wy = i / 42, wx = i - wy * 42;
      int yy = y0 - 1 + wy, xx = wx - 1;
      float v = 0.f;
      if ((unsigned)yy < (unsigned)HH && (unsigned)xx < (unsigned)WW) v = plane[yy * WW + xx];
      win[i] = v;
    }
    __syncthreads();
    const float* wrow = w + ((size_t)co0 * C2 + ci) * 9;
#pragma unroll
    for (int co = 0; co < TCO; ++co) {
      const float* wc = wrow + (size_t)co * C2 * 9;
#pragma unroll
      for (int ky = 0; ky < 3; ++ky)
#pragma unroll
        for (int kx = 0; kx < 3; ++kx)
          acc[co] += wc[ky * 3 + kx] * win[(ly + ky) * 42 + (lx + kx)];
    }
  }
  int p = (y0 + ly) * WW + lx;
#pragma unroll
  for (int co = 0; co < TCO; ++co) {
    float v = acc[co];
    v = ACT ? tanhf(v) : 1.f / (1.f + __expf(-v));
    out[(size_t)nb * CO_TOTAL * PP + (co0 + co) * PP + p] = v;
  }
}

__global__ void k_rh(float* __restrict__ gates, const float* __restrict__ nodes) {
  int i = blockIdx.x * 256 + threadIdx.x;
  int nb = i / (CC * PP);
  int rem = i - nb * (CC * PP);
  int ga = nb * C2 * PP + rem;
  gates[ga] = gates[ga] * nodes[i];
}

__global__ void k_update(const float* __restrict__ gates, const float* __restrict__ cand,
                         float* __restrict__ nodes) {
  int i = blockIdx.x * 256 + threadIdx.x;
  int nb = i / (CC * PP);
  int rem = i - nb * (CC * PP);
  float z = gates[nb * C2 * PP + CC * PP + rem];
  float h = nodes[i];
  nodes[i] = (1.f - z) * h + z * cand[i];
}

extern "C" void kernel_launch(void* const* d_in, const int* in_sizes, int n_in,
                              void* d_out, int out_size, void* d_ws, size_t ws_size,
                              hipStream_t stream) {
  const float* nodes_in = (const float*)d_in[0];
  const float* tw = (const float*)d_in[1];
  const float* tb = (const float*)d_in[2];
  const float* gw = (const float*)d_in[3];
  const float* gb = (const float*)d_in[4];
  const float* cw = (const float*)d_in[5];
  const float* cb = (const float*)d_in[6];

  float* nodes = (float*)d_out;                      // fp32 state [12][256][1600]
  char* ws = (char*)d_ws;
  // phase overlays (total 78.64 MB):
  ushort_t* nodes_bf_t = (ushort_t*)ws;              // R0: 9.83 MB (attn phase)
  ushort_t* th_t = (ushort_t*)(ws + 9830400);        // R1: 9.83 MB (attn phase)
  ushort_t* v_all = (ushort_t*)(ws + 19660800);      // R2: 19.66 MB (attn phase)
  float* agg_t = (float*)(ws + 39321600);            // R3: 39.32 MB (attn phase)
  float* agg   = (float*)(ws + 19660800);            // = R2 (conv phase)
  float* gates = (float*)(ws + 39321600);            // = R3 (conv phase)
  float* cand  = (float*)ws;                         // = R0+R1 (conv phase)

  k_copy<<<NODESZ / 256, 256, 0, stream>>>(nodes_in, nodes);
  for (int pass = 0; pass < 2; ++pass) {
    k_theta<<<dim3(5, NBB * (CC / TO)), 320, 0, stream>>>(nodes, tw, tb, th_t);
    k_to_bf_t<<<dim3(50, 8, NBB), 256, 0, stream>>>(nodes, nodes_bf_t);
    k_prep_v<<<(2 * NODESZ) / 256, 256, 0, stream>>>(nodes, v_all);
    k_attn_mfma<<<dim3(25, NBB, 2), 256, 0, stream>>>(nodes_bf_t, th_t, v_all, agg_t);
    k_aggsum_t<<<dim3(8, 50, NBB), 256, 0, stream>>>(agg_t, agg);
    k_conv<C2, 0><<<dim3(5, NBB * (C2 / TCO)), 320, 0, stream>>>(agg, nodes, CC * PP, gw, gb, gates);
    k_rh<<<NODESZ / 256, 256, 0, stream>>>(gates, nodes);
    k_conv<CC, 1><<<dim3(5, NBB * (CC / TCO)), 320, 0, stream>>>(agg, gates, C2 * PP, cw, cb, cand);
    k_update<<<NODESZ / 256, 256, 0, stream>>>(gates, cand, nodes);
  }
}

// Round 5
// 1583.453 us; speedup vs baseline: 9.4912x; 6.0725x over previous
//
#include <hip/hip_runtime.h>
#include <hip/hip_bf16.h>
#include <math.h>

#define NN 3
#define BB 4
#define CC 256
#define C2 512
#define HH 40
#define WW 40
#define PP 1600
#define NBB 12                  // NN*BB
#define NODESZ (NBB*CC*PP)      // 4,915,200
#define TO 16                   // theta: output channels per block
#define PAD 1764                // 42*42 padded pixels

typedef short short8 __attribute__((ext_vector_type(8)));
typedef float f32x4 __attribute__((ext_vector_type(4)));
typedef unsigned short ushort_t;
typedef unsigned int uint_t;

__device__ __forceinline__ ushort_t f2bf(float x) {
  union { float f; uint_t u; } v; v.f = x;
  uint_t r = v.u + 0x7fff + ((v.u >> 16) & 1);
  return (ushort_t)(r >> 16);
}

__device__ __forceinline__ void async_ld16(const ushort_t* g, ushort_t* l) {
  __builtin_amdgcn_global_load_lds(
      (const __attribute__((address_space(1))) uint_t*)g,
      (__attribute__((address_space(3))) uint_t*)l, 16, 0, 0);
}

__global__ void k_copy(const float* __restrict__ in, float* __restrict__ out) {
  int i = blockIdx.x * 256 + threadIdx.x;
  out[i] = in[i];
}

// th_t[nb][p][c] (bf16) = tb[o] + sum_c tw[o,c] * nodes[nb,c,p]
__global__ void k_theta(const float* __restrict__ nodes, const float* __restrict__ tw,
                        const float* __restrict__ tb, ushort_t* __restrict__ th_t) {
  __shared__ float w[TO * CC];
  int t = threadIdx.x;
  int nb = blockIdx.y / (CC / TO);
  int o0 = (blockIdx.y % (CC / TO)) * TO;
  for (int i = t; i < TO * CC; i += 320) w[i] = tw[(o0 + (i >> 8)) * CC + (i & 255)];
  __syncthreads();
  int p = blockIdx.x * 320 + t;
  const float* src = nodes + nb * CC * PP + p;
  float acc[TO];
#pragma unroll
  for (int o = 0; o < TO; ++o) acc[o] = tb[o0 + o];
  for (int c = 0; c < CC; c += 4) {
    float v0 = src[c * PP], v1 = src[(c + 1) * PP], v2 = src[(c + 2) * PP], v3 = src[(c + 3) * PP];
#pragma unroll
    for (int o = 0; o < TO; ++o) {
      const float4 ww = *(const float4*)(w + o * CC + c);
      acc[o] += ww.x * v0 + ww.y * v1 + ww.z * v2 + ww.w * v3;
    }
  }
  size_t base = ((size_t)nb * PP + p) * CC + o0;
#pragma unroll
  for (int o = 0; o < TO; o += 2) {
    uint_t lo = f2bf(acc[o]), hi = f2bf(acc[o + 1]);
    *(uint_t*)&th_t[base + o] = lo | (hi << 16);
  }
}

// nodes [12][256][1600] fp32 -> nodes_bf_t [12][1600][256] bf16 (transpose)
__global__ void k_to_bf_t(const float* __restrict__ src, ushort_t* __restrict__ dst) {
  __shared__ float tile[32][33];
  int nb = blockIdx.z;
  int c0 = blockIdx.y * 32;
  int pp0 = blockIdx.x * 32;
  int tx = threadIdx.x & 31, ty = threadIdx.x >> 5;
#pragma unroll
  for (int i = 0; i < 4; ++i)
    tile[ty + 8 * i][tx] = src[((size_t)nb * CC + c0 + ty + 8 * i) * PP + pp0 + tx];
  __syncthreads();
#pragma unroll
  for (int i = 0; i < 4; ++i)
    dst[((size_t)nb * PP + pp0 + ty + 8 * i) * CC + c0 + tx] = f2bf(tile[tx][ty + 8 * i]);
}

// v_all[e][b][c][p] (bf16) = nodes[recv(e),b,c,p] + nodes[send(e),b,c,p]
__global__ void k_prep_v(const float* __restrict__ nodes, ushort_t* __restrict__ v_all) {
  int i = blockIdx.x * 256 + threadIdx.x;   // 6*4*256*1600
  int eb = i / (CC * PP);
  int rem = i - eb * (CC * PP);
  int e = eb >> 2, b = eb & 3;
  int n = e >> 1, jidx = e & 1;
  int js = jidx + (jidx >= n ? 1 : 0);
  float v = nodes[((size_t)(n * BB + b)) * CC * PP + rem] +
            nodes[((size_t)(js * BB + b)) * CC * PP + rem];
  v_all[i] = f2bf(v);
}

// Fused flash attention (unchanged, verified round 3)
__global__ __launch_bounds__(256, 2) void k_attn_mfma(
    const ushort_t* __restrict__ nodes_bf_t,  // [12][1600][256]
    const ushort_t* __restrict__ th_t,        // [12][1600][256]
    const ushort_t* __restrict__ v_all,       // [6][4][256][1600]
    float* __restrict__ agg_t)                // [2][12][1600][256]
{
  __shared__ float Sf[64 * 36];
  __shared__ ushort_t Sp[64 * 40];
  __shared__ float Mst[64], Lst[64], Al[64];

  const int t = threadIdx.x;
  const int w = t >> 6;
  const int l = t & 63;
  const int quad = l >> 4;
  const int l16 = l & 15;
  const int p0 = blockIdx.x * 64;
  const int nb = blockIdx.y;
  const int jidx = blockIdx.z;
  const int n = nb >> 2, b = nb & 3;
  const int e = n * 2 + jidx;
  const int js = jidx + (jidx >= n ? 1 : 0);

  const ushort_t* thp = th_t + ((size_t)nb * PP + p0) * CC;
  const ushort_t* ejq = nodes_bf_t + ((size_t)(js * BB + b) * PP) * CC;  // [q][c]
  const ushort_t* vp  = v_all + ((size_t)(e * BB + b) * CC) * PP;        // [c][q]

  if (t < 64) { Mst[t] = -3.0e38f; Lst[t] = 0.f; }

  short8 Ath[8];
  {
    const ushort_t* arow = thp + (size_t)(16 * w + l16) * CC + quad * 8;
#pragma unroll
    for (int ks = 0; ks < 8; ++ks) Ath[ks] = *(const short8*)(arow + ks * 32);
  }
  __syncthreads();

  f32x4 O[4][4];
#pragma unroll
  for (int mt = 0; mt < 4; ++mt)
#pragma unroll
    for (int nt = 0; nt < 4; ++nt)
#pragma unroll
      for (int r = 0; r < 4; ++r) O[mt][nt][r] = 0.f;

  for (int q0 = 0; q0 < PP; q0 += 32) {
    f32x4 S0, S1;
#pragma unroll
    for (int r = 0; r < 4; ++r) { S0[r] = 0.f; S1[r] = 0.f; }
    const ushort_t* brow = ejq + (size_t)(q0 + l16) * CC + quad * 8;
#pragma unroll
    for (int ks = 0; ks < 8; ++ks) {
      short8 B0 = *(const short8*)(brow + ks * 32);
      short8 B1 = *(const short8*)(brow + 16 * CC + ks * 32);
      S0 = __builtin_amdgcn_mfma_f32_16x16x32_bf16(Ath[ks], B0, S0, 0, 0, 0);
      S1 = __builtin_amdgcn_mfma_f32_16x16x32_bf16(Ath[ks], B1, S1, 0, 0, 0);
    }
    {
      int srow = 16 * w + quad * 4;
#pragma unroll
      for (int r = 0; r < 4; ++r) {
        Sf[(srow + r) * 36 + l16] = S0[r];
        Sf[(srow + r) * 36 + 16 + l16] = S1[r];
      }
    }
    __syncthreads();
    {
      int r = t >> 2, g = (t & 3) * 8;
      float* row = Sf + r * 36 + g;
      float m = row[0];
#pragma unroll
      for (int k = 1; k < 8; ++k) m = fmaxf(m, row[k]);
      m = fmaxf(m, __shfl_xor(m, 1));
      m = fmaxf(m, __shfl_xor(m, 2));
      float Mo = Mst[r];
      float Mn = fmaxf(Mo, m);
      float alpha = __expf(Mo - Mn);
      float s = 0.f;
      ushort_t* sp = Sp + r * 40 + g;
#pragma unroll
      for (int k = 0; k < 8; ++k) {
        float ev = __expf(row[k] - Mn);
        s += ev;
        sp[k] = f2bf(ev);
      }
      s += __shfl_xor(s, 1);
      s += __shfl_xor(s, 2);
      if ((t & 3) == 0) { Lst[r] = Lst[r] * alpha + s; Mst[r] = Mn; Al[r] = alpha; }
    }
    __syncthreads();
#pragma unroll
    for (int mt = 0; mt < 4; ++mt) {
#pragma unroll
      for (int r = 0; r < 4; ++r) {
        float a = Al[16 * mt + quad * 4 + r];
#pragma unroll
        for (int nt = 0; nt < 4; ++nt) O[mt][nt][r] *= a;
      }
    }
    short8 Ap[4], Bv[4];
#pragma unroll
    for (int mt = 0; mt < 4; ++mt)
      Ap[mt] = *(const short8*)(Sp + (16 * mt + l16) * 40 + quad * 8);
    {
      const ushort_t* vrow = vp + (size_t)(64 * w + l16) * PP + q0 + quad * 8;
#pragma unroll
      for (int nt = 0; nt < 4; ++nt)
        Bv[nt] = *(const short8*)(vrow + (size_t)(16 * nt) * PP);
    }
#pragma unroll
    for (int mt = 0; mt < 4; ++mt)
#pragma unroll
      for (int nt = 0; nt < 4; ++nt)
        O[mt][nt] = __builtin_amdgcn_mfma_f32_16x16x32_bf16(Ap[mt], Bv[nt], O[mt][nt], 0, 0, 0);
    __syncthreads();
  }
  float* ao = agg_t + (((size_t)jidx * NBB + nb) * PP + p0) * CC;
#pragma unroll
  for (int mt = 0; mt < 4; ++mt) {
#pragma unroll
    for (int r = 0; r < 4; ++r) {
      int m = 16 * mt + quad * 4 + r;
      float inv = 1.f / Lst[m];
      float* dst = ao + (size_t)m * CC + 64 * w + l16;
#pragma unroll
      for (int nt = 0; nt < 4; ++nt) dst[16 * nt] = O[mt][nt][r] * inv;
    }
  }
}

// ---- conv prep ----

// reorder conv weights [M][512][3][3] fp32 -> [M][9][512] bf16
__global__ void k_wrep(const float* __restrict__ w, ushort_t* __restrict__ wr) {
  int i = blockIdx.x * 256 + threadIdx.x;   // M*9*512
  int ci = i & 511;
  int rest = i >> 9;                        // co*9 + tap
  int tp = rest % 9, co = rest / 9;
  wr[i] = f2bf(w[((size_t)co * 512 + ci) * 9 + tp]);
}

__global__ void k_pad_zero(ushort_t* __restrict__ xpad) {
  int i = blockIdx.x * 256 + threadIdx.x;   // 12*1764*512
  xpad[i] = 0;
}

// interior rows, ch 0..255 <- agg_t[0]+agg_t[1]  (both already [px][c])
__global__ void k_pad_agg(const float* __restrict__ agg_t, ushort_t* __restrict__ xpad) {
  int i = blockIdx.x * 256 + threadIdx.x;   // 12*1600*256
  int c = i & 255;
  int rest = i >> 8;
  int px = rest % PP, nb = rest / PP;
  int y = px / 40, x = px - y * 40;
  size_t src = ((size_t)nb * PP + px) * CC + c;
  float v = agg_t[src] + agg_t[(size_t)NBB * PP * CC + src];
  xpad[((size_t)nb * PAD + (y + 1) * 42 + (x + 1)) * C2 + c] = f2bf(v);
}

// interior rows, ch 256..511 <- transpose of srcA [nb][256][1600]
// MODE 0: val = h[c][px];  MODE 1: val = h[c][px] * r[c][px]
// tile[a][b] = (channel c0+a, pixel pp0+b); store value tile[tx][ty+8i]
// (= channel c0+tx, pixel pp0+ty+8i) at dest(pixel pp0+ty+8i, channel c0+tx).
template <int MODE>
__global__ void k_pad_tr(const float* __restrict__ srcA, const float* __restrict__ srcB,
                         ushort_t* __restrict__ xpad) {
  __shared__ float tile[32][33];
  int nb = blockIdx.z;
  int c0 = blockIdx.y * 32;
  int pp0 = blockIdx.x * 32;
  int tx = threadIdx.x & 31, ty = threadIdx.x >> 5;
#pragma unroll
  for (int i = 0; i < 4; ++i) {
    int c = c0 + ty + 8 * i;
    float v = srcA[((size_t)nb * CC + c) * PP + pp0 + tx];
    if (MODE == 1) v *= srcB[((size_t)nb * C2 + c) * PP + pp0 + tx];  // r-gate
    tile[ty + 8 * i][tx] = v;
  }
  __syncthreads();
#pragma unroll
  for (int i = 0; i < 4; ++i) {
    int px = pp0 + ty + 8 * i;
    int y = px / 40, x = px - y * 40;
    xpad[((size_t)nb * PAD + (y + 1) * 42 + (x + 1)) * C2 + CC + c0 + tx] =
        f2bf(tile[tx][ty + 8 * i]);
  }
}

// Implicit-GEMM conv3x3, M=co, N=px(1600), K=9 taps x 512 ci.
// Block: 128co x 128px, 4 waves (2x2), each 64x64 (4x4 16x16x32 frags).
// ACT 0: out = sigmoid(acc+bias) -> gates [nb][512][1600]
// ACT 1: v = tanh(acc+bias); z = zsrc[256+co]; out(nodes) = (1-z)h + z*v
template <int ACT>
__global__ __launch_bounds__(256) void k_conv_mfma(
    const ushort_t* __restrict__ xpad,   // [12][1764][512]
    const ushort_t* __restrict__ wr,     // [M][9*512]
    const float* __restrict__ bias,      // [M]
    const float* __restrict__ zsrc,      // gates (ACT1)
    float* __restrict__ out)
{
  __shared__ ushort_t Asm[128 * 32];
  __shared__ ushort_t Bsm[128 * 32];
  const int t = threadIdx.x;
  const int w = t >> 6, l = t & 63, quad = l >> 4, l16 = l & 15;
  const int nb = blockIdx.z;
  const int m0 = blockIdx.y * 128;
  const int px0 = blockIdx.x * 128;
  const int wm = (w >> 1) * 64, wn = (w & 1) * 64;

  // --- staging source setup (lane l covers rows 32w + l/4 and +16) ---
  const int lr = l >> 2;
  const int swf = (lr ^ (lr >> 2)) & 3;          // fill-side XOR swizzle
  const int lk = ((l & 3) ^ swf) * 8;            // k-part (shorts)
  const ushort_t* wsrc = wr + (size_t)(m0 + 32 * w + lr) * 4608 + lk;
  int pxa = px0 + 32 * w + lr;      if (pxa > 1599) pxa = 1599;
  int pxb = pxa + 16;               if (pxb > 1599) pxb = 1599;
  {
    int d = px0 + 32 * w + 16 + lr; if (d <= 1599) pxb = d;
  }
  const int ya = pxa / 40, xa = pxa - ya * 40;
  const int yb = pxb / 40, xb = pxb - yb * 40;
  const ushort_t* bsrc_a = xpad + ((size_t)nb * PAD + ya * 42 + xa) * C2 + lk;
  const ushort_t* bsrc_b = xpad + ((size_t)nb * PAD + yb * 42 + xb) * C2 + lk;
  ushort_t* Ad0 = Asm + w * 1024;   // wave-uniform LDS base; HW adds lane*16B
  ushort_t* Ad1 = Asm + w * 1024 + 512;
  ushort_t* Bd0 = Bsm + w * 1024;
  ushort_t* Bd1 = Bsm + w * 1024 + 512;

  // --- frag-read swizzle (row&15 == l16 on both A and B) ---
  const int swr = (l16 ^ (l16 >> 2)) & 3;
  const int fk = ((quad ^ swr) * 8);

  f32x4 acc[4][4];
#pragma unroll
  for (int mt = 0; mt < 4; ++mt)
#pragma unroll
    for (int nt = 0; nt < 4; ++nt)
#pragma unroll
      for (int r = 0; r < 4; ++r) acc[mt][nt][r] = 0.f;

  for (int tap = 0; tap < 9; ++tap) {
    const int ky = tap / 3, kx = tap - ky * 3;
    const int boff = (ky * 42 + kx) * C2;
    const ushort_t* wtap = wsrc + tap * 512;
#pragma unroll 1
    for (int c0 = 0; c0 < 512; c0 += 32) {
      __syncthreads();
      async_ld16(wtap + c0, Ad0);
      async_ld16(wtap + 16 * 4608 + c0, Ad1);
      async_ld16(bsrc_a + boff + c0, Bd0);
      async_ld16(bsrc_b + boff + c0, Bd1);
      __syncthreads();
      short8 Af[4], Bf[4];
#pragma unroll
      for (int mt = 0; mt < 4; ++mt)
        Af[mt] = *(const short8*)(Asm + (wm + mt * 16 + l16) * 32 + fk);
#pragma unroll
      for (int nt = 0; nt < 4; ++nt)
        Bf[nt] = *(const short8*)(Bsm + (wn + nt * 16 + l16) * 32 + fk);
#pragma unroll
      for (int mt = 0; mt < 4; ++mt)
#pragma unroll
        for (int nt = 0; nt < 4; ++nt)
          acc[mt][nt] = __builtin_amdgcn_mfma_f32_16x16x32_bf16(Af[mt], Bf[nt], acc[mt][nt], 0, 0, 0);
    }
  }

  // --- epilogue ---
#pragma unroll
  for (int mt = 0; mt < 4; ++mt) {
#pragma unroll
    for (int r = 0; r < 4; ++r) {
      int co = m0 + wm + mt * 16 + quad * 4 + r;
      float bv = bias[co];
#pragma unroll
      for (int nt = 0; nt < 4; ++nt) {
        int px = px0 + wn + nt * 16 + l16;
        if (px >= PP) continue;
        float v = acc[mt][nt][r] + bv;
        if (ACT == 0) {
          out[((size_t)nb * C2 + co) * PP + px] = 1.f / (1.f + __expf(-v));
        } else {
          v = tanhf(v);
          float z = zsrc[((size_t)nb * C2 + CC + co) * PP + px];
          float* hp = out + ((size_t)nb * CC + co) * PP + px;
          float h = *hp;
          *hp = (1.f - z) * h + z * v;
        }
      }
    }
  }
}

extern "C" void kernel_launch(void* const* d_in, const int* in_sizes, int n_in,
                              void* d_out, int out_size, void* d_ws, size_t ws_size,
                              hipStream_t stream) {
  const float* nodes_in = (const float*)d_in[0];
  const float* tw = (const float*)d_in[1];
  const float* tb = (const float*)d_in[2];
  const float* gw = (const float*)d_in[3];
  const float* gb = (const float*)d_in[4];
  const float* cw = (const float*)d_in[5];
  const float* cb = (const float*)d_in[6];

  float* nodes = (float*)d_out;                      // fp32 state [12][256][1600]
  char* ws = (char*)d_ws;
  // ---- phase overlays (max 78.64 MB) ----
  // attn phase: R0 nodes_bf_t 9.83 | R1 th_t 9.83 | R2 v_all 19.66 | R3 agg_t 39.32
  // conv phase: R0 w_g_r 4.72 + w_c_r 2.36 | R1+R2 xh_pad 21.68 | R3 gates 39.32
  ushort_t* nodes_bf_t = (ushort_t*)ws;
  ushort_t* th_t  = (ushort_t*)(ws + 9830400);
  ushort_t* v_all = (ushort_t*)(ws + 19660800);
  float*    agg_t = (float*)(ws + 39321600);
  ushort_t* w_g_r = (ushort_t*)ws;
  ushort_t* w_c_r = (ushort_t*)(ws + 4718592);
  ushort_t* xh_pad = (ushort_t*)(ws + 9830400);      // 12*1764*512*2 = 21,676,032
  float*    gates = (float*)(ws + 39321600);

  k_copy<<<NODESZ / 256, 256, 0, stream>>>(nodes_in, nodes);
  for (int pass = 0; pass < 2; ++pass) {
    // ---- attention ----
    k_theta<<<dim3(5, NBB * (CC / TO)), 320, 0, stream>>>(nodes, tw, tb, th_t);
    k_to_bf_t<<<dim3(50, 8, NBB), 256, 0, stream>>>(nodes, nodes_bf_t);
    k_prep_v<<<(2 * NODESZ) / 256, 256, 0, stream>>>(nodes, v_all);
    k_attn_mfma<<<dim3(25, NBB, 2), 256, 0, stream>>>(nodes_bf_t, th_t, v_all, agg_t);
    // ---- conv prep (attn scratch now dead) ----
    k_wrep<<<(C2 * 9 * C2) / 256, 256, 0, stream>>>(gw, w_g_r);
    k_wrep<<<(CC * 9 * C2) / 256, 256, 0, stream>>>(cw, w_c_r);
    k_pad_zero<<<(NBB * PAD * C2) / 256, 256, 0, stream>>>(xh_pad);
    k_pad_agg<<<(NBB * PP * CC) / 256, 256, 0, stream>>>(agg_t, xh_pad);
    k_pad_tr<0><<<dim3(50, 8, NBB), 256, 0, stream>>>(nodes, nullptr, xh_pad);
    // ---- gates conv ----
    k_conv_mfma<0><<<dim3(13, 4, NBB), 256, 0, stream>>>(xh_pad, w_g_r, gb, nullptr, gates);
    // ---- r*h into xh_pad high channels ----
    k_pad_tr<1><<<dim3(50, 8, NBB), 256, 0, stream>>>(nodes, gates, xh_pad);
    // ---- cand conv + fused GRU update ----
    k_conv_mfma<1><<<dim3(13, 2, NBB), 256, 0, stream>>>(xh_pad, w_c_r, cb, gates, nodes);
  }
}